// Round 1
// baseline (752.310 us; speedup 1.0000x reference)
//
#include <hip/hip_runtime.h>
#include <hip/hip_bf16.h>

// Problem constants
#define NB    1024   // batch
#define SEQ   512    // max seq len
#define DIM   128    // embedding dim (D)
#define HID   128    // hidden (H)
#define NGATE 512    // 4*H
#define NOPS  16     // OPS
#define FEAT  144    // H + OPS
#define BQ    4      // samples per workgroup
#define AST   144    // LDS row stride (bf16 elems) for x/h buffers: breaks bank conflicts

typedef __bf16 bf16x8 __attribute__((ext_vector_type(8)));
typedef float  floatx4 __attribute__((ext_vector_type(4)));

__device__ __forceinline__ float fsig(float x)  { return 1.0f / (1.0f + __expf(-x)); }
__device__ __forceinline__ float ftanhf(float x){ return 2.0f / (1.0f + __expf(-2.0f * x)) - 1.0f; }

// One workgroup = 512 threads (8 waves) owns BQ=4 samples end-to-end.
// Weights (W_ih | W_hh as concatenated K=256) live in registers as MFMA
// B-fragments: wave w owns gate tiles nt = 4w..4w+3 (16 gates each).
__global__ __launch_bounds__(512, 2)
void lstm_fused(const int* __restrict__ tokens, const int* __restrict__ lengths,
                const float* __restrict__ onehot, const float* __restrict__ emb,
                const float* __restrict__ Wih, const float* __restrict__ Whh,
                const float* __restrict__ bih, const float* __restrict__ bhh,
                const float* __restrict__ h0, const float* __restrict__ c0,
                const float* __restrict__ linW, const float* __restrict__ linb,
                float* __restrict__ out)
{
    __shared__ __align__(16) __bf16 xbuf[BQ * AST];
    __shared__ __align__(16) __bf16 hbuf[BQ * AST];
    __shared__ __align__(16) float  gbuf[BQ * NGATE];
    __shared__ __align__(16) float  hlbuf[BQ * HID];

    const int tid  = threadIdx.x;
    const int wave = tid >> 6;
    const int lane = tid & 63;
    const int quad = lane >> 4;
    const int lrow = lane & 15;
    const int bid  = blockIdx.x;

    // ---- Load weight B-fragments into registers (once). ----
    // B-operand layout (16x16x32): lane holds B[k = quad*8 + j][n = lane&15],
    // i.e. W[gate = nt*16 + lrow][k...k+7] -- contiguous in W's row.
    bf16x8 wf[4][8];
#pragma unroll
    for (int i = 0; i < 4; ++i) {
        const int g = (wave * 4 + i) * 16 + lrow;
#pragma unroll
        for (int kt = 0; kt < 8; ++kt) {
            const float* src = (kt < 4) ? (Wih + g * DIM + kt * 32 + quad * 8)
                                        : (Whh + g * HID + (kt - 4) * 32 + quad * 8);
            float4 a = *(const float4*)(src);
            float4 b = *(const float4*)(src + 4);
            bf16x8 v;
            v[0] = (__bf16)a.x; v[1] = (__bf16)a.y; v[2] = (__bf16)a.z; v[3] = (__bf16)a.w;
            v[4] = (__bf16)b.x; v[5] = (__bf16)b.y; v[6] = (__bf16)b.z; v[7] = (__bf16)b.w;
            wf[i][kt] = v;
        }
    }

    // ---- Per-thread (sample, unit) assignment for the state update. ----
    const int m = tid >> 7;    // sample within tile: 0..3
    const int u = tid & 127;   // hidden unit: 0..127
    const int b = bid * BQ + m;

    const float bI = bih[u]       + bhh[u];
    const float bF = bih[128 + u] + bhh[128 + u];
    const float bG = bih[256 + u] + bhh[256 + u];
    const float bO = bih[384 + u] + bhh[384 + u];

    int len = lengths[b]; if (len < 1) len = 1;
    const int tlast = len - 1;
    int Lmax = 0;
#pragma unroll
    for (int s2 = 0; s2 < BQ; ++s2) {
        int l2 = lengths[bid * BQ + s2]; if (l2 < 1) l2 = 1;
        Lmax = (l2 > Lmax) ? l2 : Lmax;
    }

    float c  = c0[u];
    float hl = 0.0f;
    hbuf[m * AST + u] = (__bf16)h0[u];
    // prefetch embedding row element for t=0
    float e = emb[(size_t)tokens[b * SEQ] * DIM + u];

    // A-operand row: replicate samples 0..3 across rows 4..15 (outputs ignored)
    const int ma = lrow & 3;

    __syncthreads();

    for (int t = 0; t < Lmax; ++t) {
        // stage x(t) = relu(emb row) as bf16; prefetch next row
        xbuf[m * AST + u] = (__bf16)fmaxf(e, 0.0f);
        if (t + 1 < Lmax) e = emb[(size_t)tokens[b * SEQ + t + 1] * DIM + u];
        __syncthreads();   // x(t), h(t) visible

        // A-fragments: A[m][k], k<128 from xbuf, k>=128 from hbuf
        bf16x8 af[8];
#pragma unroll
        for (int kt = 0; kt < 4; ++kt)
            af[kt] = *(const bf16x8*)&xbuf[ma * AST + kt * 32 + quad * 8];
#pragma unroll
        for (int kt = 0; kt < 4; ++kt)
            af[4 + kt] = *(const bf16x8*)&hbuf[ma * AST + kt * 32 + quad * 8];

        floatx4 acc[4];
#pragma unroll
        for (int i = 0; i < 4; ++i) {
            floatx4 a0 = {0.f, 0.f, 0.f, 0.f};
#pragma unroll
            for (int kt = 0; kt < 8; ++kt)
                a0 = __builtin_amdgcn_mfma_f32_16x16x32_bf16(af[kt], wf[i][kt], a0, 0, 0, 0);
            acc[i] = a0;
        }

        // C/D layout: col = lane&15 (gate), row = quad*4 + r (sample); valid rows on quad 0
        if (quad == 0) {
#pragma unroll
            for (int i = 0; i < 4; ++i) {
                const int col = (wave * 4 + i) * 16 + lrow;
#pragma unroll
                for (int r = 0; r < 4; ++r)
                    gbuf[r * NGATE + col] = acc[i][r];
            }
        }
        __syncthreads();   // gates visible; all A-reads retired

        // per-(sample,unit) LSTM cell update; c stays in a register
        const float gi = gbuf[m * NGATE + u]       + bI;
        const float gf = gbuf[m * NGATE + 128 + u] + bF;
        const float gg = gbuf[m * NGATE + 256 + u] + bG;
        const float go = gbuf[m * NGATE + 384 + u] + bO;
        const float ii = fsig(gi), ff = fsig(gf), g2 = ftanhf(gg), oo = fsig(go);
        c = ff * c + ii * g2;
        const float h = oo * ftanhf(c);
        if (t == tlast) hl = fmaxf(h, 0.0f);
        hbuf[m * AST + u] = (__bf16)h;   // h(t+1) for next step's A-load
    }

    // ---- epilogue: out[b] = [relu(h_last) | onehot] @ linW^T + linb ----
    hlbuf[m * HID + u] = hl;
    __syncthreads();
    if (tid < 2 * BQ) {
        const int mm = tid >> 1, kk = tid & 1;
        const int bb = bid * BQ + mm;
        float a2 = linb[kk];
        for (int q = 0; q < HID; ++q)
            a2 += hlbuf[mm * HID + q] * linW[kk * FEAT + q];
        for (int o = 0; o < NOPS; ++o)
            a2 += onehot[bb * NOPS + o] * linW[kk * FEAT + HID + o];
        out[bb * 2 + kk] = a2;
    }
}

extern "C" void kernel_launch(void* const* d_in, const int* in_sizes, int n_in,
                              void* d_out, int out_size, void* d_ws, size_t ws_size,
                              hipStream_t stream) {
    const int*   tokens  = (const int*)d_in[0];
    const int*   lengths = (const int*)d_in[1];
    const float* onehot  = (const float*)d_in[2];
    const float* emb     = (const float*)d_in[3];
    const float* Wih     = (const float*)d_in[4];
    const float* Whh     = (const float*)d_in[5];
    const float* bih     = (const float*)d_in[6];
    const float* bhh     = (const float*)d_in[7];
    const float* h0      = (const float*)d_in[8];
    const float* c0      = (const float*)d_in[9];
    const float* linW    = (const float*)d_in[10];
    const float* linb    = (const float*)d_in[11];
    float* out = (float*)d_out;
    (void)in_sizes; (void)n_in; (void)out_size; (void)d_ws; (void)ws_size;

    lstm_fused<<<dim3(NB / BQ), dim3(512), 0, stream>>>(
        tokens, lengths, onehot, emb, Wih, Whh, bih, bhh, h0, c0, linW, linb, out);
}

// Round 2
// 599.664 us; speedup vs baseline: 1.2546x; 1.2546x over previous
//
#include <hip/hip_runtime.h>
#include <hip/hip_bf16.h>

// Problem constants
#define NB    1024   // batch
#define SEQ   512    // max seq len
#define DIM   128    // embedding dim (D)
#define HID   128    // hidden (H)
#define NGATE 512    // 4*H
#define NOPS  16     // OPS
#define FEAT  144    // H + OPS
#define BQ    4      // samples per workgroup
#define AST   144    // LDS row stride (bf16 elems): breaks power-of-2 bank strides

typedef __bf16 bf16x8 __attribute__((ext_vector_type(8)));
typedef float  floatx4 __attribute__((ext_vector_type(4)));

__device__ __forceinline__ float fsig(float x)  { return 1.0f / (1.0f + __expf(-x)); }
__device__ __forceinline__ float ftanhf(float x){ return 2.0f / (1.0f + __expf(-2.0f * x)) - 1.0f; }

// One workgroup = 512 threads (8 waves) owns BQ=4 samples end-to-end.
// Wave w owns unit-chunk w (units w*16..w*16+15) for ALL 4 gate types, so the
// gates it computes via MFMA are consumed in-register (no gate LDS roundtrip).
// A rows replicate samples as m>>2, so C/D rows quad*4+r all map to sample
// `quad` -> lane (quad,lrow) extracts acc[gt][0] directly. x and h LDS buffers
// are double-buffered -> exactly ONE barrier per timestep.
__global__ __launch_bounds__(512, 2)
void lstm_fused(const int* __restrict__ tokens, const int* __restrict__ lengths,
                const float* __restrict__ onehot, const float* __restrict__ emb,
                const float* __restrict__ Wih, const float* __restrict__ Whh,
                const float* __restrict__ bih, const float* __restrict__ bhh,
                const float* __restrict__ h0, const float* __restrict__ c0,
                const float* __restrict__ linW, const float* __restrict__ linb,
                float* __restrict__ out)
{
    __shared__ __align__(16) __bf16 xbuf[2][BQ * AST];
    __shared__ __align__(16) __bf16 hbuf[2][BQ * AST];
    __shared__ __align__(16) float  hlbuf[BQ * HID];

    const int tid  = threadIdx.x;
    const int wave = tid >> 6;
    const int lane = tid & 63;
    const int quad = lane >> 4;
    const int lrow = lane & 15;
    const int bid  = blockIdx.x;

    // ---- Load weight B-fragments into registers (once). ----
    // B-layout (16x16x32): lane holds B[k=quad*8+j][n=lrow].
    // Gate for (gt, this wave, lrow): g = gt*128 + wave*16 + lrow.
    bf16x8 wf[4][8];
#pragma unroll
    for (int gt = 0; gt < 4; ++gt) {
        const int g = gt * 128 + wave * 16 + lrow;
#pragma unroll
        for (int kt = 0; kt < 8; ++kt) {
            const float* src = (kt < 4) ? (Wih + g * DIM + kt * 32 + quad * 8)
                                        : (Whh + g * HID + (kt - 4) * 32 + quad * 8);
            float4 a = *(const float4*)(src);
            float4 b = *(const float4*)(src + 4);
            bf16x8 v;
            v[0] = (__bf16)a.x; v[1] = (__bf16)a.y; v[2] = (__bf16)a.z; v[3] = (__bf16)a.w;
            v[4] = (__bf16)b.x; v[5] = (__bf16)b.y; v[6] = (__bf16)b.z; v[7] = (__bf16)b.w;
            wf[gt][kt] = v;
        }
    }

    // ---- Per-lane state: sample = quad, unit = wave*16 + lrow ----
    const int uu = wave * 16 + lrow;
    const int bq = bid * BQ + quad;
    int lenq = lengths[bq]; if (lenq < 1) lenq = 1;
    const int tlast = lenq - 1;

    int Lmax = 0;
#pragma unroll
    for (int s2 = 0; s2 < BQ; ++s2) {
        int l2 = lengths[bid * BQ + s2]; if (l2 < 1) l2 = 1;
        Lmax = (l2 > Lmax) ? l2 : Lmax;
    }

    float bini[4];
#pragma unroll
    for (int gt = 0; gt < 4; ++gt)
        bini[gt] = bih[gt * 128 + uu] + bhh[gt * 128 + uu];

    float c  = c0[uu];
    float hl = 0.0f;

    // ---- Staging thread layout: m = tid>>7 (sample), u = tid&127 (unit) ----
    const int m  = tid >> 7;
    const int u  = tid & 127;
    const int bm = bid * BQ + m;

    hbuf[0][m * AST + u] = (__bf16)h0[u];
    float e = emb[(size_t)tokens[bm * SEQ] * DIM + u];     // t = 0
    xbuf[0][m * AST + u] = (__bf16)fmaxf(e, 0.0f);
    if (Lmax > 1) e = emb[(size_t)tokens[bm * SEQ + 1] * DIM + u];  // t = 1

    const int arow = lrow >> 2;   // A row m -> sample m>>2
    __syncthreads();

    for (int t = 0; t < Lmax; ++t) {
        const int p = t & 1;
        const __bf16* xr = xbuf[p];
        const __bf16* hr = hbuf[p];

        // A-fragments: A[m=lrow][k=quad*8+j]; k<128 from x, k>=128 from h
        bf16x8 af[8];
        const int abase = arow * AST + quad * 8;
#pragma unroll
        for (int kt = 0; kt < 4; ++kt)
            af[kt] = *(const bf16x8*)&xr[abase + kt * 32];
#pragma unroll
        for (int kt = 0; kt < 4; ++kt)
            af[4 + kt] = *(const bf16x8*)&hr[abase + kt * 32];

        // stage x(t+1) into the other buffer; prefetch e for t+2 (off-chain)
        if (t + 1 < Lmax) {
            xbuf[1 - p][m * AST + u] = (__bf16)fmaxf(e, 0.0f);
            if (t + 2 < Lmax) e = emb[(size_t)tokens[bm * SEQ + t + 2] * DIM + u];
        }

        floatx4 acc[4];
#pragma unroll
        for (int gt = 0; gt < 4; ++gt) {
            floatx4 a0 = {bini[gt], bini[gt], bini[gt], bini[gt]};
            acc[gt] = a0;
        }
#pragma unroll
        for (int kt = 0; kt < 8; ++kt)
#pragma unroll
            for (int gt = 0; gt < 4; ++gt)
                acc[gt] = __builtin_amdgcn_mfma_f32_16x16x32_bf16(af[kt], wf[gt][kt], acc[gt], 0, 0, 0);

        // C/D: col=lrow (unit), row=quad*4+r -> sample quad for ALL r; take r=0.
        const float ii = fsig(acc[0][0]);
        const float ff = fsig(acc[1][0]);
        const float g2 = ftanhf(acc[2][0]);
        const float oo = fsig(acc[3][0]);
        c = ff * c + ii * g2;
        const float h = oo * ftanhf(c);
        if (t == tlast) hl = fmaxf(h, 0.0f);
        hbuf[1 - p][quad * AST + uu] = (__bf16)h;

        __syncthreads();   // h(t) + x(t+1) visible; all reads of buffers p retired
    }

    // ---- epilogue: out[b] = [relu(h_last) | onehot] @ linW^T + linb ----
    hlbuf[quad * HID + uu] = hl;
    __syncthreads();
    if (tid < 2 * BQ) {
        const int mm = tid >> 1, kk = tid & 1;
        const int bb = bid * BQ + mm;
        float a2 = linb[kk];
        for (int q = 0; q < HID; ++q)
            a2 += hlbuf[mm * HID + q] * linW[kk * FEAT + q];
        for (int o = 0; o < NOPS; ++o)
            a2 += onehot[bb * NOPS + o] * linW[kk * FEAT + HID + o];
        out[bb * 2 + kk] = a2;
    }
}

extern "C" void kernel_launch(void* const* d_in, const int* in_sizes, int n_in,
                              void* d_out, int out_size, void* d_ws, size_t ws_size,
                              hipStream_t stream) {
    const int*   tokens  = (const int*)d_in[0];
    const int*   lengths = (const int*)d_in[1];
    const float* onehot  = (const float*)d_in[2];
    const float* emb     = (const float*)d_in[3];
    const float* Wih     = (const float*)d_in[4];
    const float* Whh     = (const float*)d_in[5];
    const float* bih     = (const float*)d_in[6];
    const float* bhh     = (const float*)d_in[7];
    const float* h0      = (const float*)d_in[8];
    const float* c0      = (const float*)d_in[9];
    const float* linW    = (const float*)d_in[10];
    const float* linb    = (const float*)d_in[11];
    float* out = (float*)d_out;
    (void)in_sizes; (void)n_in; (void)out_size; (void)d_ws; (void)ws_size;

    lstm_fused<<<dim3(NB / BQ), dim3(512), 0, stream>>>(
        tokens, lengths, onehot, emb, Wih, Whh, bih, bhh, h0, c0, linW, linb, out);
}

// Round 3
// 582.184 us; speedup vs baseline: 1.2922x; 1.0300x over previous
//
#include <hip/hip_runtime.h>
#include <hip/hip_bf16.h>

// Problem constants
#define NB    1024   // batch
#define SEQ   512    // max seq len
#define DIM   128    // embedding dim (D)
#define HID   128    // hidden (H)
#define NGATE 512    // 4*H
#define NOPS  16     // OPS
#define FEAT  144    // H + OPS
#define BQ    4      // samples per workgroup
#define AST   144    // LDS row stride (bf16 elems): breaks power-of-2 bank strides

typedef __bf16 bf16x8 __attribute__((ext_vector_type(8)));
typedef float  floatx4 __attribute__((ext_vector_type(4)));

__device__ __forceinline__ float fsig(float x)  { return 1.0f / (1.0f + __expf(-x)); }
__device__ __forceinline__ float ftanhf(float x){ return 2.0f / (1.0f + __expf(-2.0f * x)) - 1.0f; }

// One WG = 512 threads (8 waves) owns BQ=4 samples. Wave w owns unit-chunk w
// for all 4 gate types (gates consumed in-register, no gate LDS roundtrip).
// SOFTWARE PIPELINE: gates(t) = [bias + x(t)@W_ih^T]  (computed at END of step
// t-1, off the critical path)  +  h(t)@W_hh^T (the only serial part). Critical
// chain per step: barrier -> read h-frags -> 16 h-MFMAs -> activation -> write.
// The 16 x-MFMAs for t+1 fill the MFMA pipe during the activation/barrier
// shadow. One barrier per step; x and h LDS buffers double-buffered by parity.
__global__ __launch_bounds__(512, 2)
void lstm_fused(const int* __restrict__ tokens, const int* __restrict__ lengths,
                const float* __restrict__ onehot, const float* __restrict__ emb,
                const float* __restrict__ Wih, const float* __restrict__ Whh,
                const float* __restrict__ bih, const float* __restrict__ bhh,
                const float* __restrict__ h0, const float* __restrict__ c0,
                const float* __restrict__ linW, const float* __restrict__ linb,
                float* __restrict__ out)
{
    __shared__ __align__(16) __bf16 xbuf[2][BQ * AST];
    __shared__ __align__(16) __bf16 hbuf[2][BQ * AST];
    __shared__ __align__(16) float  hlbuf[BQ * HID];

    const int tid  = threadIdx.x;
    const int wave = tid >> 6;
    const int lane = tid & 63;
    const int quad = lane >> 4;
    const int lrow = lane & 15;
    const int bid  = blockIdx.x;

    // ---- Weight B-fragments in registers (loaded once). ----
    // B-layout (16x16x32): lane holds B[k=quad*8+j][n=lrow].
    // wfx = W_ih (x-part, K 0..127), wfh = W_hh (h-part, K 128..255).
    bf16x8 wfx[4][4], wfh[4][4];
#pragma unroll
    for (int gt = 0; gt < 4; ++gt) {
        const int g = gt * 128 + wave * 16 + lrow;
#pragma unroll
        for (int kt = 0; kt < 4; ++kt) {
            const float* sx = Wih + g * DIM + kt * 32 + quad * 8;
            const float* sh = Whh + g * HID + kt * 32 + quad * 8;
            float4 a = *(const float4*)(sx);
            float4 b = *(const float4*)(sx + 4);
            bf16x8 v;
            v[0] = (__bf16)a.x; v[1] = (__bf16)a.y; v[2] = (__bf16)a.z; v[3] = (__bf16)a.w;
            v[4] = (__bf16)b.x; v[5] = (__bf16)b.y; v[6] = (__bf16)b.z; v[7] = (__bf16)b.w;
            wfx[gt][kt] = v;
            a = *(const float4*)(sh);
            b = *(const float4*)(sh + 4);
            v[0] = (__bf16)a.x; v[1] = (__bf16)a.y; v[2] = (__bf16)a.z; v[3] = (__bf16)a.w;
            v[4] = (__bf16)b.x; v[5] = (__bf16)b.y; v[6] = (__bf16)b.z; v[7] = (__bf16)b.w;
            wfh[gt][kt] = v;
        }
    }

    // ---- Per-lane state: sample = quad, unit = wave*16 + lrow ----
    const int uu = wave * 16 + lrow;
    const int bq = bid * BQ + quad;
    int lenq = lengths[bq]; if (lenq < 1) lenq = 1;
    const int tlast = lenq - 1;

    int Lmax = 0;
#pragma unroll
    for (int s2 = 0; s2 < BQ; ++s2) {
        int l2 = lengths[bid * BQ + s2]; if (l2 < 1) l2 = 1;
        Lmax = (l2 > Lmax) ? l2 : Lmax;
    }

    float bini[4];
#pragma unroll
    for (int gt = 0; gt < 4; ++gt)
        bini[gt] = bih[gt * 128 + uu] + bhh[gt * 128 + uu];

    float c  = c0[uu];
    float hl = 0.0f;

    // ---- Staging thread layout: m = tid>>7 (sample), u = tid&127 (unit) ----
    const int m  = tid >> 7;
    const int u  = tid & 127;
    const int bm = bid * BQ + m;
    const int sm = m * AST + u;

    hbuf[0][sm] = (__bf16)h0[u];
    {
        float e0 = emb[(size_t)tokens[bm * SEQ] * DIM + u];
        xbuf[0][sm] = (__bf16)fmaxf(e0, 0.0f);
        if (Lmax > 1) {
            float e1 = emb[(size_t)tokens[bm * SEQ + 1] * DIM + u];
            xbuf[1][sm] = (__bf16)fmaxf(e1, 0.0f);
        }
    }
    float e = 0.0f;
    if (Lmax > 2) e = emb[(size_t)tokens[bm * SEQ + 2] * DIM + u];

    const int arow  = lrow >> 2;          // A row m -> sample m>>2
    const int abase = arow * AST + quad * 8;

    __syncthreads();   // x(0), x(1), h(0) staged

    // ---- Prologue: acc_x(0) = bias + x(0) @ W_ih^T ----
    floatx4 accx[4];
    {
        bf16x8 af[4];
#pragma unroll
        for (int kt = 0; kt < 4; ++kt)
            af[kt] = *(const bf16x8*)&xbuf[0][abase + kt * 32];
#pragma unroll
        for (int gt = 0; gt < 4; ++gt) {
            floatx4 a0 = {bini[gt], bini[gt], bini[gt], bini[gt]};
            accx[gt] = a0;
        }
#pragma unroll
        for (int kt = 0; kt < 4; ++kt)
#pragma unroll
            for (int gt = 0; gt < 4; ++gt)
                accx[gt] = __builtin_amdgcn_mfma_f32_16x16x32_bf16(af[kt], wfx[gt][kt], accx[gt], 0, 0, 0);
    }
    __syncthreads();   // pre-loop x(0) reads retired before iter-0 stages x(2)

    for (int t = 0; t < Lmax; ++t) {
        const int p = t & 1;

        // C: h(t) fragments
        bf16x8 ah[4];
#pragma unroll
        for (int kt = 0; kt < 4; ++kt)
            ah[kt] = *(const bf16x8*)&hbuf[p][abase + kt * 32];

        // D: gates(t) = acc_x(t) + h(t) @ W_hh^T   (the serial MFMAs)
        floatx4 acc[4];
#pragma unroll
        for (int gt = 0; gt < 4; ++gt) acc[gt] = accx[gt];
#pragma unroll
        for (int kt = 0; kt < 4; ++kt)
#pragma unroll
            for (int gt = 0; gt < 4; ++gt)
                acc[gt] = __builtin_amdgcn_mfma_f32_16x16x32_bf16(ah[kt], wfh[gt][kt], acc[gt], 0, 0, 0);

        // E: cell update. C/D rows quad*4+r all = sample quad -> take elem 0.
        const float ii = fsig(acc[0][0]);
        const float ff = fsig(acc[1][0]);
        const float g2 = ftanhf(acc[2][0]);
        const float oo = fsig(acc[3][0]);
        c = ff * c + ii * g2;
        const float h = oo * ftanhf(c);
        if (t == tlast) hl = fmaxf(h, 0.0f);

        // F: h(t+1) -> other parity buffer
        hbuf[1 - p][quad * AST + uu] = (__bf16)h;

        // G: stage x(t+2) into xbuf[p] (x(t) reads finished last iter); e(t+3)
        if (t + 2 < Lmax) {
            xbuf[p][sm] = (__bf16)fmaxf(e, 0.0f);
            if (t + 3 < Lmax) e = emb[(size_t)tokens[bm * SEQ + t + 3] * DIM + u];
        }

        // H+I: pre-compute acc_x(t+1) = bias + x(t+1) @ W_ih^T (fills pipe
        // bubble while other waves finish activation / wait at barrier)
        if (t + 1 < Lmax) {
            bf16x8 af[4];
#pragma unroll
            for (int kt = 0; kt < 4; ++kt)
                af[kt] = *(const bf16x8*)&xbuf[1 - p][abase + kt * 32];
#pragma unroll
            for (int gt = 0; gt < 4; ++gt) {
                floatx4 a0 = {bini[gt], bini[gt], bini[gt], bini[gt]};
                accx[gt] = a0;
            }
#pragma unroll
            for (int kt = 0; kt < 4; ++kt)
#pragma unroll
                for (int gt = 0; gt < 4; ++gt)
                    accx[gt] = __builtin_amdgcn_mfma_f32_16x16x32_bf16(af[kt], wfx[gt][kt], accx[gt], 0, 0, 0);
        }

        // J: single barrier per step
        __syncthreads();
    }

    // ---- epilogue: out[b] = [relu(h_last) | onehot] @ linW^T + linb ----
    hlbuf[quad * HID + uu] = hl;
    __syncthreads();
    if (tid < 2 * BQ) {
        const int mm = tid >> 1, kk = tid & 1;
        const int bb = bid * BQ + mm;
        float a2 = linb[kk];
        for (int q = 0; q < HID; ++q)
            a2 += hlbuf[mm * HID + q] * linW[kk * FEAT + q];
        for (int o = 0; o < NOPS; ++o)
            a2 += onehot[bb * NOPS + o] * linW[kk * FEAT + HID + o];
        out[bb * 2 + kk] = a2;
    }
}

extern "C" void kernel_launch(void* const* d_in, const int* in_sizes, int n_in,
                              void* d_out, int out_size, void* d_ws, size_t ws_size,
                              hipStream_t stream) {
    const int*   tokens  = (const int*)d_in[0];
    const int*   lengths = (const int*)d_in[1];
    const float* onehot  = (const float*)d_in[2];
    const float* emb     = (const float*)d_in[3];
    const float* Wih     = (const float*)d_in[4];
    const float* Whh     = (const float*)d_in[5];
    const float* bih     = (const float*)d_in[6];
    const float* bhh     = (const float*)d_in[7];
    const float* h0      = (const float*)d_in[8];
    const float* c0      = (const float*)d_in[9];
    const float* linW    = (const float*)d_in[10];
    const float* linb    = (const float*)d_in[11];
    float* out = (float*)d_out;
    (void)in_sizes; (void)n_in; (void)out_size; (void)d_ws; (void)ws_size;

    lstm_fused<<<dim3(NB / BQ), dim3(512), 0, stream>>>(
        tokens, lengths, onehot, emb, Wih, Whh, bih, bhh, h0, c0, linW, linb, out);
}